// Round 1
// baseline (80.330 us; speedup 1.0000x reference)
//
#include <hip/hip_runtime.h>

#define TPB 256
#define QPT 8                     // queries per thread
#define QPB (TPB * QPT)           // 2048 queries per block
#define NSLICE 8
#define NPTS 8192
#define SLICE_N (NPTS / NSLICE)   // 1024 targets per slice
#define BS 4
#define TOTQ (2 * BS * NPTS)      // 65536 total queries (both directions)

// Pack (p0,p1,p2) -> (p0,p1,p2,||p||^2)
__global__ __launch_bounds__(TPB) void pack_kernel(const float* __restrict__ x,
                                                   const float* __restrict__ y,
                                                   float4* __restrict__ px,
                                                   float4* __restrict__ py) {
    int i = blockIdx.x * TPB + threadIdx.x;   // 0 .. BS*NPTS-1
    if (i < BS * NPTS) {
        float x0 = x[i * 3 + 0], x1 = x[i * 3 + 1], x2 = x[i * 3 + 2];
        px[i] = make_float4(x0, x1, x2, x0 * x0 + x1 * x1 + x2 * x2);
        float y0 = y[i * 3 + 0], y1 = y[i * 3 + 1], y2 = y[i * 3 + 2];
        py[i] = make_float4(y0, y1, y2, y0 * y0 + y1 * y1 + y2 * y2);
    }
}

// Per (query-group, target-slice): min over slice of (||t||^2 - 2 q.t), + ||q||^2
// partial[s*TOTQ + Q] = min_sq over targets in slice s
__global__ __launch_bounds__(TPB) void chamfer_min_kernel(const float4* __restrict__ px,
                                                          const float4* __restrict__ py,
                                                          float* __restrict__ partial) {
    __shared__ float4 tile[SLICE_N];   // 16 KB
    const int t = threadIdx.x;
    const int g = blockIdx.x >> 3;     // query group 0..31
    const int s = blockIdx.x & 7;      // target slice 0..7
    const int dir = g >> 4;            // 0: queries=x targets=y; 1: queries=y targets=x
    const int b = (g >> 2) & 3;        // batch
    const int chunk = g & 3;           // 2048-query chunk within batch

    const float4* q  = (dir == 0 ? px : py) + b * NPTS + chunk * QPB;
    const float4* tg = (dir == 0 ? py : px) + b * NPTS + s * SLICE_N;

    float a0[QPT], a1[QPT], a2[QPT], qq[QPT], mv[QPT];
#pragma unroll
    for (int i = 0; i < QPT; ++i) {
        float4 v = q[i * TPB + t];
        a0[i] = -2.0f * v.x;
        a1[i] = -2.0f * v.y;
        a2[i] = -2.0f * v.z;
        qq[i] = v.w;
        mv[i] = 3.4e38f;
    }

#pragma unroll
    for (int i = 0; i < SLICE_N / TPB; ++i)
        tile[i * TPB + t] = tg[i * TPB + t];
    __syncthreads();

#pragma unroll 4
    for (int j = 0; j < SLICE_N; ++j) {
        float4 v = tile[j];            // broadcast ds_read_b128, conflict-free
#pragma unroll
        for (int i = 0; i < QPT; ++i) {
            float d = fmaf(a2[i], v.z, fmaf(a1[i], v.y, fmaf(a0[i], v.x, v.w)));
            mv[i] = fminf(mv[i], d);
        }
    }

    const int qg0 = g * QPB;
#pragma unroll
    for (int i = 0; i < QPT; ++i)
        partial[(size_t)s * TOTQ + qg0 + i * TPB + t] = mv[i] + qq[i];
}

// Min over slices, sqrt, block-sum (deterministic tree)
__global__ __launch_bounds__(TPB) void combine_kernel(const float* __restrict__ partial,
                                                      float* __restrict__ bsum) {
    int idx = blockIdx.x * TPB + threadIdx.x;   // grid = TOTQ/TPB = 256
    float m = 3.4e38f;
#pragma unroll
    for (int s = 0; s < NSLICE; ++s)
        m = fminf(m, partial[(size_t)s * TOTQ + idx]);
    float d = sqrtf(fmaxf(m, 0.0f));

    __shared__ float red[TPB];
    red[threadIdx.x] = d;
    __syncthreads();
    for (int off = TPB / 2; off > 0; off >>= 1) {
        if (threadIdx.x < off) red[threadIdx.x] += red[threadIdx.x + off];
        __syncthreads();
    }
    if (threadIdx.x == 0) bsum[blockIdx.x] = red[0];
}

// Sum 256 block sums, normalize: out = total / (bs*n) = total / 32768
__global__ __launch_bounds__(TPB) void final_kernel(const float* __restrict__ bsum,
                                                    float* __restrict__ out) {
    __shared__ float red[TPB];
    red[threadIdx.x] = bsum[threadIdx.x];
    __syncthreads();
    for (int off = TPB / 2; off > 0; off >>= 1) {
        if (threadIdx.x < off) red[threadIdx.x] += red[threadIdx.x + off];
        __syncthreads();
    }
    if (threadIdx.x == 0) out[0] = red[0] * (1.0f / 32768.0f);
}

extern "C" void kernel_launch(void* const* d_in, const int* in_sizes, int n_in,
                              void* d_out, int out_size, void* d_ws, size_t ws_size,
                              hipStream_t stream) {
    const float* x = (const float*)d_in[0];
    const float* y = (const float*)d_in[1];
    float* out = (float*)d_out;
    char* ws = (char*)d_ws;

    // ws layout: px 512KB | py 512KB | partial 2MB | bsum 1KB  (total ~3MB)
    float4* px      = (float4*)(ws);
    float4* py      = (float4*)(ws + 512 * 1024);
    float*  partial = (float*)(ws + 1024 * 1024);
    float*  bsum    = (float*)(ws + 3 * 1024 * 1024);

    hipLaunchKernelGGL(pack_kernel, dim3((BS * NPTS + TPB - 1) / TPB), dim3(TPB), 0, stream,
                       x, y, px, py);
    hipLaunchKernelGGL(chamfer_min_kernel, dim3(32 * NSLICE), dim3(TPB), 0, stream,
                       px, py, partial);
    hipLaunchKernelGGL(combine_kernel, dim3(TOTQ / TPB), dim3(TPB), 0, stream,
                       partial, bsum);
    hipLaunchKernelGGL(final_kernel, dim3(1), dim3(TPB), 0, stream,
                       bsum, out);
}

// Round 2
// 60.252 us; speedup vs baseline: 1.3332x; 1.3332x over previous
//
#include <hip/hip_runtime.h>

#define TPB 256
#define QPT 8                     // queries per thread
#define QPB (TPB * QPT)           // 2048 queries per block
#define NPTS 8192
#define BS 4
#define TOTQ (2 * BS * NPTS)      // 65536 total queries (both directions)
#define NGROUP (TOTQ / QPB)       // 32 query groups

// Pack (p0,p1,p2) -> (p0,p1,p2,||p||^2)
__global__ __launch_bounds__(TPB) void pack_kernel(const float* __restrict__ x,
                                                   const float* __restrict__ y,
                                                   float4* __restrict__ px,
                                                   float4* __restrict__ py) {
    int i = blockIdx.x * TPB + threadIdx.x;   // 0 .. BS*NPTS-1
    if (i < BS * NPTS) {
        float x0 = x[i * 3 + 0], x1 = x[i * 3 + 1], x2 = x[i * 3 + 2];
        px[i] = make_float4(x0, x1, x2, x0 * x0 + x1 * x1 + x2 * x2);
        float y0 = y[i * 3 + 0], y1 = y[i * 3 + 1], y2 = y[i * 3 + 2];
        py[i] = make_float4(y0, y1, y2, y0 * y0 + y1 * y1 + y2 * y2);
    }
}

// Per (query-group, target-slice): min over slice of (||t||^2 - 2 q.t), + ||q||^2
// partial[s*TOTQ + Q] = min_sq over targets in slice s
// NS slices -> grid = NGROUP*NS blocks; NS=16 gives 2 blocks/CU (2 waves/SIMD)
template <int NS>
__global__ __launch_bounds__(TPB) void chamfer_min_kernel(const float4* __restrict__ px,
                                                          const float4* __restrict__ py,
                                                          float* __restrict__ partial) {
    constexpr int SLICE = NPTS / NS;
    __shared__ float4 tile[SLICE];
    const int t = threadIdx.x;
    const int g = blockIdx.x / NS;     // query group 0..31
    const int s = blockIdx.x % NS;     // target slice
    const int dir = g >> 4;            // 0: queries=x targets=y; 1: queries=y targets=x
    const int b = (g >> 2) & 3;        // batch
    const int chunk = g & 3;           // 2048-query chunk within batch

    const float4* q  = (dir == 0 ? px : py) + b * NPTS + chunk * QPB;
    const float4* tg = (dir == 0 ? py : px) + b * NPTS + s * SLICE;

    float a0[QPT], a1[QPT], a2[QPT], qq[QPT], mv[QPT];
#pragma unroll
    for (int i = 0; i < QPT; ++i) {
        float4 v = q[i * TPB + t];
        a0[i] = -2.0f * v.x;
        a1[i] = -2.0f * v.y;
        a2[i] = -2.0f * v.z;
        qq[i] = v.w;
        mv[i] = 3.4e38f;
    }

#pragma unroll
    for (int i = 0; i < SLICE / TPB; ++i)
        tile[i * TPB + t] = tg[i * TPB + t];
    __syncthreads();

#pragma unroll 2
    for (int j = 0; j < SLICE; j += 2) {
        float4 v0 = tile[j];           // broadcast ds_read_b128, conflict-free
        float4 v1 = tile[j + 1];
#pragma unroll
        for (int i = 0; i < QPT; ++i) {
            float d0 = fmaf(a2[i], v0.z, fmaf(a1[i], v0.y, fmaf(a0[i], v0.x, v0.w)));
            float d1 = fmaf(a2[i], v1.z, fmaf(a1[i], v1.y, fmaf(a0[i], v1.x, v1.w)));
            mv[i] = fminf(fminf(mv[i], d0), d1);   // -> v_min3_f32
        }
    }

    const int qg0 = g * QPB;
#pragma unroll
    for (int i = 0; i < QPT; ++i)
        partial[(size_t)s * TOTQ + qg0 + i * TPB + t] = mv[i] + qq[i];
}

// Min over slices, sqrt, block-sum (deterministic tree)
template <int NS>
__global__ __launch_bounds__(TPB) void combine_kernel(const float* __restrict__ partial,
                                                      float* __restrict__ bsum) {
    int idx = blockIdx.x * TPB + threadIdx.x;   // grid = TOTQ/TPB = 256
    float m = 3.4e38f;
#pragma unroll
    for (int s = 0; s < NS; ++s)
        m = fminf(m, partial[(size_t)s * TOTQ + idx]);
    float d = sqrtf(fmaxf(m, 0.0f));

    __shared__ float red[TPB];
    red[threadIdx.x] = d;
    __syncthreads();
    for (int off = TPB / 2; off > 0; off >>= 1) {
        if (threadIdx.x < off) red[threadIdx.x] += red[threadIdx.x + off];
        __syncthreads();
    }
    if (threadIdx.x == 0) bsum[blockIdx.x] = red[0];
}

// Sum 256 block sums, normalize: out = total / (bs*n) = total / 32768
__global__ __launch_bounds__(TPB) void final_kernel(const float* __restrict__ bsum,
                                                    float* __restrict__ out) {
    __shared__ float red[TPB];
    red[threadIdx.x] = bsum[threadIdx.x];
    __syncthreads();
    for (int off = TPB / 2; off > 0; off >>= 1) {
        if (threadIdx.x < off) red[threadIdx.x] += red[threadIdx.x + off];
        __syncthreads();
    }
    if (threadIdx.x == 0) out[0] = red[0] * (1.0f / 32768.0f);
}

extern "C" void kernel_launch(void* const* d_in, const int* in_sizes, int n_in,
                              void* d_out, int out_size, void* d_ws, size_t ws_size,
                              hipStream_t stream) {
    const float* x = (const float*)d_in[0];
    const float* y = (const float*)d_in[1];
    float* out = (float*)d_out;
    char* ws = (char*)d_ws;

    // ws layout: px 512KB | py 512KB | partial NS*256KB | bsum 1KB
    float4* px      = (float4*)(ws);
    float4* py      = (float4*)(ws + 512 * 1024);
    float*  partial = (float*)(ws + 1024 * 1024);

    hipLaunchKernelGGL(pack_kernel, dim3((BS * NPTS + TPB - 1) / TPB), dim3(TPB), 0, stream,
                       x, y, px, py);

    const size_t need16 = 1024 * 1024 + (size_t)16 * TOTQ * 4 + 1024;
    if (ws_size >= need16) {
        constexpr int NS = 16;   // 512 blocks -> 2 blocks/CU -> 2 waves/SIMD
        float* bsum = (float*)(ws + 1024 * 1024 + (size_t)NS * TOTQ * 4);
        hipLaunchKernelGGL((chamfer_min_kernel<NS>), dim3(NGROUP * NS), dim3(TPB), 0, stream,
                           px, py, partial);
        hipLaunchKernelGGL((combine_kernel<NS>), dim3(TOTQ / TPB), dim3(TPB), 0, stream,
                           partial, bsum);
        hipLaunchKernelGGL(final_kernel, dim3(1), dim3(TPB), 0, stream, bsum, out);
    } else {
        constexpr int NS = 8;    // fallback if workspace is small
        float* bsum = (float*)(ws + 1024 * 1024 + (size_t)NS * TOTQ * 4);
        hipLaunchKernelGGL((chamfer_min_kernel<NS>), dim3(NGROUP * NS), dim3(TPB), 0, stream,
                           px, py, partial);
        hipLaunchKernelGGL((combine_kernel<NS>), dim3(TOTQ / TPB), dim3(TPB), 0, stream,
                           partial, bsum);
        hipLaunchKernelGGL(final_kernel, dim3(1), dim3(TPB), 0, stream, bsum, out);
    }
}